// Round 7
// baseline (173.444 us; speedup 1.0000x reference)
//
#include <hip/hip_runtime.h>
#include <stdint.h>

#define COLUMNS   1024
#define CELLS     16
#define NUM_CELLS (COLUMNS * CELLS)   // 16384
#define SEGS      32
#define SYNS      128
#define ACT_THR   10
#define NB        2048                // blocks for the big scans
#define NWAVES    (NB * 4)            // 256-thread blocks = 4 waves

typedef int            i32x4 __attribute__((ext_vector_type(4)));
typedef float          f32x4 __attribute__((ext_vector_type(4)));
typedef unsigned short u16x4 __attribute__((ext_vector_type(4)));

template<typename T>
__device__ __forceinline__ T ntload(const T* p) { return __builtin_nontemporal_load(p); }

// Pack prev (bool, dtype auto-detected) into 512-word LDS bitmask.
// Returns per-thread "any nonzero word" flag accumulation via s_any.
__device__ __forceinline__ void pack_prev_lds(
    const void* __restrict__ prev, uint32_t* sbits, int* s_isu8, int* s_any)
{
    const int t = threadIdx.x;
    const int* pi = (const int*)prev;
    // int32-bool: first 4096 words all 0/1. uint8-bool: random bytes -> word >1 whp.
    int bad = 0;
    for (int k = t; k < NUM_CELLS / 4; k += 256)
        bad |= ((unsigned)pi[k] > 1u) ? 1 : 0;
    unsigned long long bb = __ballot(bad != 0);
    if ((t & 63) == 0 && bb) atomicOr(s_isu8, 1);
    __syncthreads();
    const int isu8 = *s_isu8;
    int any = 0;
    for (int w = t; w < NUM_CELLS / 32; w += 256) {
        uint32_t m = 0;
        if (isu8) {
            const unsigned char* p = (const unsigned char*)prev + (size_t)w * 32;
            #pragma unroll
            for (int j = 0; j < 32; ++j) m |= (p[j] ? 1u : 0u) << j;
        } else {
            const int* p = pi + (size_t)w * 32;
            #pragma unroll
            for (int j = 0; j < 32; ++j) m |= (p[j] ? 1u : 0u) << j;
        }
        sbits[w] = m;
        any |= (m != 0) ? 1 : 0;
    }
    if (s_any) {
        unsigned long long ba = __ballot(any != 0);
        if ((threadIdx.x & 63) == 0 && ba) atomicOr(s_any, 1);
    }
}

// ---------------------------------------------------------------------------
// K1 = plan + phases 1+2: per-block prev pack, then persistent wave-per-cell
// scan over ALL cells (wave-uniform x check). Ballot reduction. Writes pred1,
// bestseg, and (PACK) the uint16 sideband {clipped conn | connected<<14}.
// ---------------------------------------------------------------------------
template<bool PACK>
__global__ __launch_bounds__(256) void k1_kernel(
    const void* __restrict__ prev, const int* __restrict__ x,
    const int* __restrict__ conn, const float* __restrict__ vol,
    const float* __restrict__ cons, unsigned short* __restrict__ packed,
    unsigned char* __restrict__ pred1, unsigned char* __restrict__ bestseg)
{
    __shared__ uint32_t sbits[NUM_CELLS / 32];
    __shared__ int s_isu8;
    if (threadIdx.x == 0) s_isu8 = 0;
    __syncthreads();
    pack_prev_lds(prev, sbits, &s_isu8, nullptr);
    __syncthreads();

    const int wv   = threadIdx.x >> 6;
    const int ln   = threadIdx.x & 63;
    const int half = ln >> 5;
    const int l32  = ln & 31;
    const int gw   = blockIdx.x * 4 + wv;

    for (int cell = gw; cell < NUM_CELLS; cell += NWAVES) {
        if (x[cell >> 4] == 0) continue;
        const size_t base = (size_t)cell * (SEGS * SYNS);
        int fire = 0, bestkey = 0;
        #pragma unroll 4
        for (int k = 0; k < 16; ++k) {
            const int segA = k * 2;               // lanes 0-31: segA, 32-63: segA+1
            const size_t off = base + (size_t)(segA + half) * SYNS + l32 * 4;
            i32x4 c = ntload((const i32x4*)(conn + off));
            f32x4 v = ntload((const f32x4*)(vol + off));
            f32x4 q = ntload((const f32x4*)(cons + off));
            int i0 = min(max(c.x, 0), NUM_CELLS - 1);
            int i1 = min(max(c.y, 0), NUM_CELLS - 1);
            int i2 = min(max(c.z, 0), NUM_CELLS - 1);
            int i3 = min(max(c.w, 0), NUM_CELLS - 1);
            int p0 = (sbits[i0 >> 5] >> (i0 & 31)) & 1;
            int p1 = (sbits[i1 >> 5] >> (i1 & 31)) & 1;
            int p2 = (sbits[i2 >> 5] >> (i2 & 31)) & 1;
            int p3 = (sbits[i3 >> 5] >> (i3 & 31)) & 1;
            int cn0 = ((v.x > 0.5f) || (q.x > 0.5f)) ? 1 : 0;
            int cn1 = ((v.y > 0.5f) || (q.y > 0.5f)) ? 1 : 0;
            int cn2 = ((v.z > 0.5f) || (q.z > 0.5f)) ? 1 : 0;
            int cn3 = ((v.w > 0.5f) || (q.w > 0.5f)) ? 1 : 0;
            if (PACK) {
                u16x4 pk;
                pk.x = (unsigned short)(i0 | (cn0 << 14));
                pk.y = (unsigned short)(i1 | (cn1 << 14));
                pk.z = (unsigned short)(i2 | (cn2 << 14));
                pk.w = (unsigned short)(i3 | (cn3 << 14));
                *(u16x4*)(packed + off) = pk;
            }
            unsigned long long bc0 = __ballot(cn0 && p0);
            unsigned long long bc1 = __ballot(cn1 && p1);
            unsigned long long bc2 = __ballot(cn2 && p2);
            unsigned long long bc3 = __ballot(cn3 && p3);
            unsigned long long bp0 = __ballot(p0 != 0);
            unsigned long long bp1 = __ballot(p1 != 0);
            unsigned long long bp2 = __ballot(p2 != 0);
            unsigned long long bp3 = __ballot(p3 != 0);
            int cA = __popcll(bc0 & 0xFFFFFFFFull) + __popcll(bc1 & 0xFFFFFFFFull)
                   + __popcll(bc2 & 0xFFFFFFFFull) + __popcll(bc3 & 0xFFFFFFFFull);
            int cB = __popcll(bc0 >> 32) + __popcll(bc1 >> 32)
                   + __popcll(bc2 >> 32) + __popcll(bc3 >> 32);
            int oA = __popcll(bp0 & 0xFFFFFFFFull) + __popcll(bp1 & 0xFFFFFFFFull)
                   + __popcll(bp2 & 0xFFFFFFFFull) + __popcll(bp3 & 0xFFFFFFFFull);
            int oB = __popcll(bp0 >> 32) + __popcll(bp1 >> 32)
                   + __popcll(bp2 >> 32) + __popcll(bp3 >> 32);
            fire |= (cA >= ACT_THR) | (cB >= ACT_THR);
            bestkey = max(bestkey, (oA << 8) | (255 - segA));   // first-max tiebreak
            bestkey = max(bestkey, (oB << 8) | (254 - segA));
        }
        if (ln == 0) {
            pred1[cell]   = (unsigned char)(fire ? 1 : 0);
            bestseg[cell] = (unsigned char)(255 - (bestkey & 0xFF));
        }
    }
}

// ---------------------------------------------------------------------------
// K2 = mid + phase 3: per-block prologue rebuilds prevbits + newbits + s_act
// + learnflag from x/pred1/prev (L2-hot); block 0 also writes new_active
// floats and acc; then persistent wave-per-cell scan writes new_predictive
// for every cell (0 for inactive columns). PACKED path streams the sideband;
// the single updated segment re-reads vol/cons (clip(x,0,1)>0.5 == x>0.5).
// ---------------------------------------------------------------------------
template<bool PACKED>
__global__ __launch_bounds__(256) void k2_kernel(
    const void* __restrict__ prev, const int* __restrict__ x,
    const float* __restrict__ mod, const unsigned short* __restrict__ packed,
    const int* __restrict__ conn, const float* __restrict__ vol,
    const float* __restrict__ cons, const unsigned char* __restrict__ pred1,
    const unsigned char* __restrict__ bestseg, float* __restrict__ out)
{
    __shared__ uint32_t sprev[NUM_CELLS / 32];
    __shared__ uint32_t snew[NUM_CELLS / 32];
    __shared__ unsigned short s_na[COLUMNS];    // per-column new_active bits
    __shared__ unsigned char s_act[COLUMNS];
    __shared__ unsigned char s_hp[COLUMNS];
    __shared__ int s_isu8, s_anyprev, s_learn, s_nact, s_npred;
    const int t = threadIdx.x;
    if (t == 0) { s_isu8 = 0; s_anyprev = 0; s_nact = 0; s_npred = 0; }
    __syncthreads();
    pack_prev_lds(prev, sprev, &s_isu8, &s_anyprev);

    // s_act / s_hp / s_na: 4 columns per thread
    #pragma unroll
    for (int j = 0; j < 4; ++j) {
        const int col = t + j * 256;
        const int ca = (x[col] != 0) ? 1 : 0;
        uint4 pv = *(const uint4*)(pred1 + (size_t)col * CELLS);  // 16 pred1 bytes
        const int hp = ((pv.x | pv.y | pv.z | pv.w) != 0) ? 1 : 0;
        unsigned int bits = 0;
        if (ca) {
            if (hp) {
                #pragma unroll
                for (int b = 0; b < 4; ++b) {
                    unsigned int w = (&pv.x)[b];
                    bits |= ((w & 0xFFu) ? 1u : 0u) << (b * 4 + 0);
                    bits |= ((w & 0xFF00u) ? 1u : 0u) << (b * 4 + 1);
                    bits |= ((w & 0xFF0000u) ? 1u : 0u) << (b * 4 + 2);
                    bits |= ((w & 0xFF000000u) ? 1u : 0u) << (b * 4 + 3);
                }
            } else bits = 0xFFFFu;   // burst
        }
        s_na[col]  = (unsigned short)bits;
        s_act[col] = (unsigned char)ca;
        s_hp[col]  = (unsigned char)hp;
    }
    __syncthreads();
    for (int w = t; w < NUM_CELLS / 32; w += 256)
        snew[w] = (uint32_t)s_na[2 * w] | ((uint32_t)s_na[2 * w + 1] << 16);
    if (t == 0) s_learn = ((mod[0] != 0.0f) && s_anyprev) ? 1 : 0;
    __syncthreads();

    if (blockIdx.x == 0) {
        // acc + new_active floats, done once by block 0
        int c1 = 0, c2 = 0;
        for (int col = t; col < COLUMNS; col += 256) {
            c1 += s_act[col];
            c2 += s_act[col] & s_hp[col];
        }
        atomicAdd(&s_nact, c1);
        atomicAdd(&s_npred, c2);
        for (int g = t; g < NUM_CELLS / 4; g += 256) {
            const uint32_t w = snew[g >> 3];
            const int sh = (g & 7) * 4;
            f32x4 o;
            o.x = (w >> (sh + 0)) & 1 ? 1.0f : 0.0f;
            o.y = (w >> (sh + 1)) & 1 ? 1.0f : 0.0f;
            o.z = (w >> (sh + 2)) & 1 ? 1.0f : 0.0f;
            o.w = (w >> (sh + 3)) & 1 ? 1.0f : 0.0f;
            *(f32x4*)(out + (size_t)g * 4) = o;
        }
        __syncthreads();
        if (t == 0) {
            const int na = s_nact, np = s_npred;
            out[2 * NUM_CELLS] = (na > 0) ? (float)np / (float)max(na, 1) : 1.0f;
        }
    }

    const int lf   = s_learn;
    const float d  = mod[0] * 0.1f;
    const int wv   = t >> 6;
    const int ln   = t & 63;
    const int half = ln >> 5;
    const int l32  = ln & 31;
    const int gw   = blockIdx.x * 4 + wv;
    float* outpred = out + NUM_CELLS;

    for (int cell = gw; cell < NUM_CELLS; cell += NWAVES) {
        const int col = cell >> 4;
        if (!s_act[col]) {
            if (ln == 0) outpred[cell] = 0.0f;
            continue;
        }
        const size_t base = (size_t)cell * (SEGS * SYNS);
        const int na  = (snew[cell >> 5] >> (cell & 31)) & 1;
        const int upd = (lf && na) ? (int)bestseg[cell] : -1;
        int fire = 0;
        #pragma unroll 4
        for (int k = 0; k < 16; ++k) {
            const int segA = k * 2;
            const int seg  = segA + half;
            const size_t off = base + (size_t)seg * SYNS + l32 * 4;
            int i0, i1, i2, i3, cn0, cn1, cn2, cn3;
            if (PACKED) {
                u16x4 pk = *(const u16x4*)(packed + off);
                i0 = pk.x & 0x3FFF; cn0 = (pk.x >> 14) & 1;
                i1 = pk.y & 0x3FFF; cn1 = (pk.y >> 14) & 1;
                i2 = pk.z & 0x3FFF; cn2 = (pk.z >> 14) & 1;
                i3 = pk.w & 0x3FFF; cn3 = (pk.w >> 14) & 1;
                if (seg == upd) {
                    f32x4 v = *(const f32x4*)(vol + off);
                    f32x4 q = *(const f32x4*)(cons + off);
                    int pp0 = (sprev[i0 >> 5] >> (i0 & 31)) & 1;
                    int pp1 = (sprev[i1 >> 5] >> (i1 & 31)) & 1;
                    int pp2 = (sprev[i2 >> 5] >> (i2 & 31)) & 1;
                    int pp3 = (sprev[i3 >> 5] >> (i3 & 31)) & 1;
                    cn0 = ((v.x + (pp0 ? d : -d)) > 0.5f) || (q.x > 0.5f);
                    cn1 = ((v.y + (pp1 ? d : -d)) > 0.5f) || (q.y > 0.5f);
                    cn2 = ((v.z + (pp2 ? d : -d)) > 0.5f) || (q.z > 0.5f);
                    cn3 = ((v.w + (pp3 ? d : -d)) > 0.5f) || (q.w > 0.5f);
                }
            } else {
                i32x4 c = ntload((const i32x4*)(conn + off));
                f32x4 v = ntload((const f32x4*)(vol + off));
                f32x4 q = ntload((const f32x4*)(cons + off));
                i0 = min(max(c.x, 0), NUM_CELLS - 1);
                i1 = min(max(c.y, 0), NUM_CELLS - 1);
                i2 = min(max(c.z, 0), NUM_CELLS - 1);
                i3 = min(max(c.w, 0), NUM_CELLS - 1);
                float vx = v.x, vy = v.y, vz = v.z, vw = v.w;
                if (seg == upd) {
                    int pp0 = (sprev[i0 >> 5] >> (i0 & 31)) & 1;
                    int pp1 = (sprev[i1 >> 5] >> (i1 & 31)) & 1;
                    int pp2 = (sprev[i2 >> 5] >> (i2 & 31)) & 1;
                    int pp3 = (sprev[i3 >> 5] >> (i3 & 31)) & 1;
                    vx += pp0 ? d : -d; vy += pp1 ? d : -d;
                    vz += pp2 ? d : -d; vw += pp3 ? d : -d;
                }
                cn0 = (vx > 0.5f) || (q.x > 0.5f);
                cn1 = (vy > 0.5f) || (q.y > 0.5f);
                cn2 = (vz > 0.5f) || (q.z > 0.5f);
                cn3 = (vw > 0.5f) || (q.w > 0.5f);
            }
            int pn0 = (snew[i0 >> 5] >> (i0 & 31)) & 1;
            int pn1 = (snew[i1 >> 5] >> (i1 & 31)) & 1;
            int pn2 = (snew[i2 >> 5] >> (i2 & 31)) & 1;
            int pn3 = (snew[i3 >> 5] >> (i3 & 31)) & 1;
            unsigned long long b0 = __ballot(cn0 && pn0);
            unsigned long long b1 = __ballot(cn1 && pn1);
            unsigned long long b2 = __ballot(cn2 && pn2);
            unsigned long long b3 = __ballot(cn3 && pn3);
            int cA = __popcll(b0 & 0xFFFFFFFFull) + __popcll(b1 & 0xFFFFFFFFull)
                   + __popcll(b2 & 0xFFFFFFFFull) + __popcll(b3 & 0xFFFFFFFFull);
            int cB = __popcll(b0 >> 32) + __popcll(b1 >> 32)
                   + __popcll(b2 >> 32) + __popcll(b3 >> 32);
            fire |= (cA >= ACT_THR) | (cB >= ACT_THR);
        }
        if (ln == 0) outpred[cell] = fire ? 1.0f : 0.0f;
    }
}

// ---------------------------------------------------------------------------
extern "C" void kernel_launch(void* const* d_in, const int* in_sizes, int n_in,
                              void* d_out, int out_size, void* d_ws, size_t ws_size,
                              hipStream_t stream) {
    const int*   x    = (const int*)d_in[0];
    const float* mod  = (const float*)d_in[1];
    const void*  prev = d_in[2];                 // bool array (dtype auto-detected)
    const int*   conn = (const int*)d_in[3];
    const float* vol  = (const float*)d_in[4];
    const float* cons = (const float*)d_in[5];
    float* out = (float*)d_out;  // [0..N) new_active, [N..2N) new_predictive, [2N] acc

    char* ws = (char*)d_ws;
    unsigned char* pred1   = (unsigned char*)(ws + 0);      // 16 KiB
    unsigned char* bestseg = (unsigned char*)(ws + 16384);  // 16 KiB
    unsigned short* packed = (unsigned short*)(ws + 65536); // 128 MiB
    const size_t packed_bytes = (size_t)NUM_CELLS * SEGS * SYNS * 2;
    const bool use_packed = ws_size >= (size_t)65536 + packed_bytes;

    if (use_packed) {
        k1_kernel<true><<<NB, 256, 0, stream>>>(prev, x, conn, vol, cons, packed,
                                                pred1, bestseg);
        k2_kernel<true><<<NB, 256, 0, stream>>>(prev, x, mod, packed, conn, vol,
                                                cons, pred1, bestseg, out);
    } else {
        k1_kernel<false><<<NB, 256, 0, stream>>>(prev, x, conn, vol, cons, packed,
                                                 pred1, bestseg);
        k2_kernel<false><<<NB, 256, 0, stream>>>(prev, x, mod, packed, conn, vol,
                                                 cons, pred1, bestseg, out);
    }
}